// Round 8
// baseline (253.757 us; speedup 1.0000x reference)
//
#include <hip/hip_runtime.h>
#include <stdint.h>

// VectorQuantizer: N=65536 rows, D=128, K=1024 codewords, f32.
// d_out (all f32): quantized (8388608) | indices-as-float (65536) | loss (1)
//
// score = ||c||^2 - 2 x.c via bf16-split MFMA (hi*hi + hi*lo + lo*hi), fused
// top-2 + epilogue in one kernel. 8 waves/block: wave (rg,ch) = 32 rows x
// 32-cw column half -> 16 waves/CU (vs 8) at unchanged LDS/MFMA demand.
// Rows with top2-margin < MARGIN re-ranked exactly in f32 (batched repair).
// loss = 1.25*mean(||x||^2 + best_score).

typedef short     bf16x8 __attribute__((ext_vector_type(8)));
typedef float     f32x4  __attribute__((ext_vector_type(4)));
typedef unsigned short u16x8 __attribute__((ext_vector_type(8)));
typedef unsigned short u16x2 __attribute__((ext_vector_type(2)));

constexpr int N_ROWS = 65536;
constexpr int K_CODES = 1024;
constexpr int D = 128;
constexpr float MARGIN = 0.01f;   // proven R5-R7; repair is cheap (~5us)

__device__ __forceinline__ unsigned short f32_to_bf16_rn(float f) {
    unsigned u = __float_as_uint(f);
    unsigned r = (u + 0x7FFFu + ((u >> 16) & 1u)) >> 16;
    return (unsigned short)r;
}
__device__ __forceinline__ float bf16_to_f32(unsigned short h) {
    return __uint_as_float(((unsigned)h) << 16);
}

__device__ __forceinline__ void gload_lds16(const void* g, void* l) {
    __builtin_amdgcn_global_load_lds(
        (const __attribute__((address_space(1))) unsigned int*)g,
        (__attribute__((address_space(3))) unsigned int*)l, 16, 0, 0);
}

// ---------------------------------------------------------------------------
// Prep: codeword norms + bf16 hi/lo planes; zero rcnt/acc.
__global__ __launch_bounds__(64) void vq_prep_cw(const float* __restrict__ cw,
                                                 unsigned short* __restrict__ Cp,
                                                 float* __restrict__ cnorm,
                                                 int* __restrict__ rcnt,
                                                 double* __restrict__ acc) {
    const int k = blockIdx.x;
    const int lane = threadIdx.x;
    float2 v = reinterpret_cast<const float2*>(cw + (size_t)k * D)[lane];
    float s = v.x * v.x + v.y * v.y;
#pragma unroll
    for (int off = 32; off; off >>= 1) s += __shfl_down(s, off, 64);
    if (lane == 0) cnorm[k] = s;
    if (lane == 0 && k == 0) { *rcnt = 0; *acc = 0.0; }

    unsigned short hx = f32_to_bf16_rn(v.x), hy = f32_to_bf16_rn(v.y);
    unsigned short lx = f32_to_bf16_rn(v.x - bf16_to_f32(hx));
    unsigned short ly = f32_to_bf16_rn(v.y - bf16_to_f32(hy));
    size_t off0 = (size_t)k * D + lane * 2;
    u16x2 hv; hv[0] = hx; hv[1] = hy;
    u16x2 lv; lv[0] = lx; lv[1] = ly;
    *reinterpret_cast<u16x2*>(Cp + off0) = hv;
    *reinterpret_cast<u16x2*>(Cp + 131072 + off0) = lv;
}

// ---------------------------------------------------------------------------
// Fused argmin + epilogue. 512 blocks x 512 thr (8 waves).
// Wave (rg = w&3, ch = w>>2): rows rg*32..+32, column half ch (32 of 64 cw).
__global__ __launch_bounds__(512, 4) void vq_argmin_fused(
    const float* __restrict__ x,
    const unsigned short* __restrict__ Cp,
    const float* __restrict__ cnorm,
    const float* __restrict__ cw,
    float* __restrict__ out_idx_f,
    float* __restrict__ qout,
    float* __restrict__ rowloss,
    float* __restrict__ xnorm,
    int* __restrict__ rcnt,
    int* __restrict__ rrows,
    double* __restrict__ acc) {
    __shared__ unsigned char Bs[2][2][16384];  // [buf][plane][64cw * 256B swz]
    __shared__ float mv[2][128], mv2[2][128];
    __shared__ int mi[2][128];
    __shared__ int idx_s[128];
    __shared__ float xs_n[128];
    __shared__ double wsum[8];

    const int tid = threadIdx.x;
    const int wave = tid >> 6;
    const int lane = tid & 63;
    const int l15 = lane & 15;
    const int lg = lane >> 4;
    const int rg = wave & 3;   // row group
    const int ch = wave >> 2;  // column half
    const int base = blockIdx.x * 128;
    const int wrow = base + rg * 32;

    // Stage chunk c (64 cw x 2 planes = 32KB): 32 loads, 4 per wave.
    const char* Cpb = reinterpret_cast<const char*>(Cp);
    auto stageB = [&](int c, int b) {
#pragma unroll
        for (int u = 0; u < 4; ++u) {
            int t = wave * 4 + u;
            int pl = t >> 4;
            int cwl = (t & 15) * 4 + lg;
            int q = l15 * 16;
            const char* src = Cpb + pl * 262144 + ((size_t)(c * 64 + cwl)) * 256
                              + (q ^ ((cwl & 7) << 4));
            void* dst = (void*)&Bs[b][pl][(t & 15) * 1024];
            gload_lds16(src, dst);
        }
    };
    stageB(0, 0);

    // A fragments: f32 x -> bf16 hi/lo in regs; row sumsq alongside.
    // (Both column-half waves load the same A rows; only ch==0 writes norms.)
    bf16x8 A[2][4][2];
    float xn[2] = {0.f, 0.f};
#pragma unroll
    for (int r2 = 0; r2 < 2; ++r2) {
        const float* xr0 = x + (size_t)(wrow + r2 * 16 + l15) * D;
#pragma unroll
        for (int s = 0; s < 4; ++s) {
            const float4* xf = reinterpret_cast<const float4*>(xr0 + s * 32 + lg * 8);
            float4 f0 = xf[0];
            float4 f1 = xf[1];
            float in[8] = {f0.x, f0.y, f0.z, f0.w, f1.x, f1.y, f1.z, f1.w};
            u16x8 hv, lv;
#pragma unroll
            for (int e = 0; e < 8; ++e) {
                xn[r2] += in[e] * in[e];
                unsigned short h = f32_to_bf16_rn(in[e]);
                hv[e] = h;
                lv[e] = f32_to_bf16_rn(in[e] - bf16_to_f32(h));
            }
            A[r2][s][0] = *reinterpret_cast<bf16x8*>(&hv);
            A[r2][s][1] = *reinterpret_cast<bf16x8*>(&lv);
        }
    }
#pragma unroll
    for (int r2 = 0; r2 < 2; ++r2) {
        xn[r2] += __shfl_xor(xn[r2], 16, 64);
        xn[r2] += __shfl_xor(xn[r2], 32, 64);
        if (ch == 0 && lg == 0) {
            xs_n[rg * 32 + r2 * 16 + l15] = xn[r2];
            xnorm[wrow + r2 * 16 + l15] = xn[r2];
        }
    }

    float bv[2][2], bv2[2][2];
    int bi_[2][2];
#pragma unroll
    for (int r2 = 0; r2 < 2; ++r2)
#pragma unroll
        for (int i = 0; i < 2; ++i) {}
    float tv[2][4], tv2[2][4];
    int ti[2][4];
#pragma unroll
    for (int r2 = 0; r2 < 2; ++r2)
#pragma unroll
        for (int i = 0; i < 4; ++i) { tv[r2][i] = 3.4e38f; tv2[r2][i] = 3.4e38f; ti[r2][i] = 0; }

    const int cb = l15 * 256;
    const int swz = (l15 & 7) << 4;
    int kb[4];
#pragma unroll
    for (int s = 0; s < 4; ++s) kb[s] = (s * 64 + lg * 16) ^ swz;

    asm volatile("s_waitcnt vmcnt(0)" ::: "memory");
    __syncthreads();

    for (int c = 0; c < 16; ++c) {
        const int buf = c & 1;
        if (c < 15) stageB(c + 1, buf ^ 1);

        f32x4 accf[2][2];
#pragma unroll
        for (int r2 = 0; r2 < 2; ++r2)
#pragma unroll
            for (int j = 0; j < 2; ++j) accf[r2][j] = (f32x4)(0.f);

#pragma unroll
        for (int s = 0; s < 4; ++s) {
            bf16x8 bh[2], bl[2];
#pragma unroll
            for (int j = 0; j < 2; ++j) {
                int ad = (ch * 2 + j) * 4096 + cb + kb[s];
                bh[j] = *reinterpret_cast<const bf16x8*>(&Bs[buf][0][ad]);
                bl[j] = *reinterpret_cast<const bf16x8*>(&Bs[buf][1][ad]);
            }
#pragma unroll
            for (int r2 = 0; r2 < 2; ++r2)
#pragma unroll
                for (int j = 0; j < 2; ++j) {
                    accf[r2][j] = __builtin_amdgcn_mfma_f32_16x16x32_bf16(
                        A[r2][s][0], bh[j], accf[r2][j], 0, 0, 0);
                    accf[r2][j] = __builtin_amdgcn_mfma_f32_16x16x32_bf16(
                        A[r2][s][0], bl[j], accf[r2][j], 0, 0, 0);
                    accf[r2][j] = __builtin_amdgcn_mfma_f32_16x16x32_bf16(
                        A[r2][s][1], bh[j], accf[r2][j], 0, 0, 0);
                }
        }

        // scores + running top-2 (cols ascend per lane -> first-min kept)
#pragma unroll
        for (int j = 0; j < 2; ++j) {
            int col = c * 64 + (ch * 2 + j) * 16 + l15;
            float cn = cnorm[col];
#pragma unroll
            for (int r2 = 0; r2 < 2; ++r2)
#pragma unroll
                for (int i = 0; i < 4; ++i) {
                    float sc = cn - 2.f * accf[r2][j][i];
                    if (sc < tv[r2][i]) {
                        tv2[r2][i] = tv[r2][i];
                        tv[r2][i] = sc;
                        ti[r2][i] = col;
                    } else if (sc < tv2[r2][i]) {
                        tv2[r2][i] = sc;
                    }
                }
        }
        asm volatile("s_waitcnt vmcnt(0)" ::: "memory");
        __syncthreads();
    }

    // Per-wave cross-lane top-2 merge over the 16 l15 lanes; stash per half.
#pragma unroll
    for (int r2 = 0; r2 < 2; ++r2)
#pragma unroll
        for (int i = 0; i < 4; ++i) {
            float v = tv[r2][i], v2 = tv2[r2][i];
            int ix = ti[r2][i];
#pragma unroll
            for (int off = 1; off < 16; off <<= 1) {
                float ov = __shfl_xor(v, off, 64);
                float ov2 = __shfl_xor(v2, off, 64);
                int oi = __shfl_xor(ix, off, 64);
                float nv2 = fminf(fminf(v2, ov2), fmaxf(v, ov));
                if (ov < v || (ov == v && oi < ix)) { v = ov; ix = oi; }
                v2 = nv2;
            }
            if (l15 == 0) {
                int rl = rg * 32 + r2 * 16 + lg * 4 + i;
                mv[ch][rl] = v;
                mv2[ch][rl] = v2;
                mi[ch][rl] = ix;
            }
        }
    __syncthreads();

    // Cross-half merge (threads 0..127, one row each) + bookkeeping.
    double lsum = 0.0;
    if (tid < 128) {
        int row = base + tid;
        float v0 = mv[0][tid], v0b = mv2[0][tid];
        int i0 = mi[0][tid];
        float v1 = mv[1][tid], v1b = mv2[1][tid];
        int i1 = mi[1][tid];
        bool take0 = (v0 < v1) || (v0 == v1 && i0 <= i1);
        float best = take0 ? v0 : v1;
        int bidx = take0 ? i0 : i1;
        float second = take0 ? fminf(v1, v0b) : fminf(v0, v1b);

        out_idx_f[row] = (float)bidx;
        idx_s[tid] = bidx;
        float rl = xs_n[tid] + best;
        rowloss[row] = rl;
        lsum = (double)rl;
        if (second - best < MARGIN) {
            int p = atomicAdd(rcnt, 1);
            rrows[p] = row;
        }
    }

    // Block loss partial -> one f64 atomic.
#pragma unroll
    for (int off = 32; off; off >>= 1) lsum += __shfl_down(lsum, off, 64);
    if (lane == 0) wsum[wave] = lsum;
    __syncthreads();
    if (tid == 0) {
        double b = 0.0;
#pragma unroll
        for (int q = 0; q < 8; ++q) b += wsum[q];
        atomicAdd(acc, b);
    }

    // qout gather-write: 128 rows x 512B, coalesced; codebook is L2-hot.
    const float4* cw4 = reinterpret_cast<const float4*>(cw);
    float4* q4 = reinterpret_cast<float4*>(qout);
#pragma unroll
    for (int it = 0; it < 8; ++it) {
        int i = it * 512 + tid;
        int r = i >> 5, d4 = i & 31;
        q4[(size_t)(base + r) * 32 + d4] = cw4[(size_t)idx_s[r] * 32 + d4];
    }
}

// ---------------------------------------------------------------------------
// Batched exact repair: 16 flagged rows share one codebook stream. Updates
// idx/qout/rowloss; accumulates (new-old) loss deltas, 1 atomic per block.
__global__ __launch_bounds__(256) void vq_repair(const float* __restrict__ x,
                                                 const float* __restrict__ cw,
                                                 const float* __restrict__ cnorm,
                                                 const float* __restrict__ xnorm,
                                                 const int* __restrict__ rcnt,
                                                 const int* __restrict__ rrows,
                                                 float* __restrict__ out_idx_f,
                                                 float* __restrict__ qout,
                                                 float* __restrict__ rowloss,
                                                 double* __restrict__ acc) {
    __shared__ float xs[16][132];
    __shared__ int rowids[16];
    __shared__ float sval[16][16];
    __shared__ int sidx[16][16];
    __shared__ int fidx[16];

    const int t = threadIdx.x;
    const int count = *rcnt;
    const float4* cw4 = reinterpret_cast<const float4*>(cw);
    double dsum = 0.0;

    for (int g = blockIdx.x; g * 16 < count; g += 512) {
        int nrows = min(16, count - g * 16);
        __syncthreads();
        if (t < 16) rowids[t] = rrows[g * 16 + (t < nrows ? t : 0)];
        __syncthreads();
        for (int i = t; i < 512; i += 256) {
            int r = i >> 5, d4 = i & 31;
            *reinterpret_cast<float4*>(&xs[r][d4 * 4]) =
                reinterpret_cast<const float4*>(x)[(size_t)rowids[r] * 32 + d4];
        }
        __syncthreads();

        const int r = t & 15;
        const int qq = t >> 4;
        float bv = 3.4e38f;
        int bi = 0;
#pragma unroll 2
        for (int kt = 0; kt < 8; ++kt) {
            float a[8] = {0.f, 0.f, 0.f, 0.f, 0.f, 0.f, 0.f, 0.f};
            int k0 = qq * 64 + kt * 8;
            for (int d4 = 0; d4 < 32; ++d4) {
                float4 xv = *reinterpret_cast<const float4*>(&xs[r][d4 * 4]);
#pragma unroll
                for (int kk = 0; kk < 8; ++kk) {
                    float4 cv = cw4[(size_t)(k0 + kk) * 32 + d4];
                    a[kk] += xv.x * cv.x + xv.y * cv.y + xv.z * cv.z + xv.w * cv.w;
                }
            }
#pragma unroll
            for (int kk = 0; kk < 8; ++kk) {
                int k = k0 + kk;
                float sc = cnorm[k] - 2.f * a[kk];
                if (sc < bv) { bv = sc; bi = k; }
            }
        }
        sval[r][qq] = bv;
        sidx[r][qq] = bi;
        __syncthreads();
        if (t < 16) {
            float fv = sval[t][0];
            int fi = sidx[t][0];
#pragma unroll
            for (int q2 = 1; q2 < 16; ++q2) {
                float v = sval[t][q2];
                int ii = sidx[t][q2];
                if (v < fv || (v == fv && ii < fi)) { fv = v; fi = ii; }
            }
            fidx[t] = fi;
            if (t < nrows) {
                int row = rowids[t];
                out_idx_f[row] = (float)fi;
                float nrl = xnorm[row] + fv;
                float orl = rowloss[row];
                rowloss[row] = nrl;
                dsum += (double)nrl - (double)orl;
            }
        }
        __syncthreads();
        for (int i = t; i < 512; i += 256) {
            int rr = i >> 5, d4 = i & 31;
            float4 q4 = cw4[(size_t)fidx[rr] * 32 + d4];
            reinterpret_cast<float4*>(qout)[(size_t)rowids[rr] * 32 + d4] = q4;
        }
    }
#pragma unroll
    for (int off = 32; off; off >>= 1) dsum += __shfl_down(dsum, off, 64);
    __shared__ double wsum[4];
    if ((t & 63) == 0) wsum[t >> 6] = dsum;
    __syncthreads();
    if (t == 0) {
        double b = wsum[0] + wsum[1] + wsum[2] + wsum[3];
        if (b != 0.0) atomicAdd(acc, b);
    }
}

// ---------------------------------------------------------------------------
__global__ void vq_loss_final(const double* __restrict__ acc,
                              float* __restrict__ out_loss) {
    *out_loss = (float)(*acc * (1.25 / (double)((size_t)N_ROWS * D)));
}

// ---------------------------------------------------------------------------
extern "C" void kernel_launch(void* const* d_in, const int* in_sizes, int n_in,
                              void* d_out, int out_size, void* d_ws, size_t ws_size,
                              hipStream_t stream) {
    const float* x = (const float*)d_in[0];
    const float* cw = (const float*)d_in[1];

    float* qout = (float*)d_out;                                    // 8388608 f32
    float* out_idx_f = qout + (size_t)N_ROWS * D;                   // 65536 f32
    float* out_loss = out_idx_f + N_ROWS;                           // 1 f32

    char* w = (char*)d_ws;
    unsigned short* Cp = (unsigned short*)w;          w += 524288;
    float* cnorm = (float*)w;                         w += 4096;
    int* rcnt = (int*)w;                              w += 16;
    double* acc = (double*)w;                         w += 240;
    int* rrows = (int*)w;                             w += 262144;
    float* xnorm = (float*)w;                         w += 262144;
    float* rowloss = (float*)w;                       w += 262144;

    vq_prep_cw<<<K_CODES, 64, 0, stream>>>(cw, Cp, cnorm, rcnt, acc);
    vq_argmin_fused<<<N_ROWS / 128, 512, 0, stream>>>(
        x, Cp, cnorm, cw, out_idx_f, qout, rowloss, xnorm, rcnt, rrows, acc);
    vq_repair<<<512, 256, 0, stream>>>(
        x, cw, cnorm, xnorm, rcnt, rrows, out_idx_f, qout, rowloss, acc);
    vq_loss_final<<<1, 1, 0, stream>>>(acc, out_loss);
}

// Round 9
// 251.780 us; speedup vs baseline: 1.0079x; 1.0079x over previous
//
#include <hip/hip_runtime.h>
#include <stdint.h>

// VectorQuantizer: N=65536 rows, D=128, K=1024 codewords, f32.
// d_out (all f32): quantized (8388608) | indices-as-float (65536) | loss (1)
//
// score = ||c||^2 - 2 x.c via bf16-split MFMA (hi*hi + hi*lo + lo*hi), fused
// top-2 + epilogue in one kernel. 8 waves/block: wave (rg,ch) = 32 rows x
// 32-cw column half. launch_bounds(512,2): cap 256 VGPR, natural alloc ~110
// -> no spill (R8's (512,4) squeezed to 64 VGPR and spilled 120MB scratch);
// HW co-schedules 2 blocks/CU = 16 waves/CU when alloc <= 128.
// Rows with top2-margin < MARGIN re-ranked exactly in f32 (batched repair).
// loss = 1.25*mean(||x||^2 + best_score).

typedef short     bf16x8 __attribute__((ext_vector_type(8)));
typedef float     f32x4  __attribute__((ext_vector_type(4)));
typedef unsigned short u16x8 __attribute__((ext_vector_type(8)));
typedef unsigned short u16x2 __attribute__((ext_vector_type(2)));

constexpr int N_ROWS = 65536;
constexpr int K_CODES = 1024;
constexpr int D = 128;
constexpr float MARGIN = 0.01f;   // proven R5-R8; repair is cheap

__device__ __forceinline__ unsigned short f32_to_bf16_rn(float f) {
    unsigned u = __float_as_uint(f);
    unsigned r = (u + 0x7FFFu + ((u >> 16) & 1u)) >> 16;
    return (unsigned short)r;
}
__device__ __forceinline__ float bf16_to_f32(unsigned short h) {
    return __uint_as_float(((unsigned)h) << 16);
}

__device__ __forceinline__ void gload_lds16(const void* g, void* l) {
    __builtin_amdgcn_global_load_lds(
        (const __attribute__((address_space(1))) unsigned int*)g,
        (__attribute__((address_space(3))) unsigned int*)l, 16, 0, 0);
}

// ---------------------------------------------------------------------------
// Prep: codeword norms + bf16 hi/lo planes; zero rcnt/acc.
__global__ __launch_bounds__(64) void vq_prep_cw(const float* __restrict__ cw,
                                                 unsigned short* __restrict__ Cp,
                                                 float* __restrict__ cnorm,
                                                 int* __restrict__ rcnt,
                                                 double* __restrict__ acc) {
    const int k = blockIdx.x;
    const int lane = threadIdx.x;
    float2 v = reinterpret_cast<const float2*>(cw + (size_t)k * D)[lane];
    float s = v.x * v.x + v.y * v.y;
#pragma unroll
    for (int off = 32; off; off >>= 1) s += __shfl_down(s, off, 64);
    if (lane == 0) cnorm[k] = s;
    if (lane == 0 && k == 0) { *rcnt = 0; *acc = 0.0; }

    unsigned short hx = f32_to_bf16_rn(v.x), hy = f32_to_bf16_rn(v.y);
    unsigned short lx = f32_to_bf16_rn(v.x - bf16_to_f32(hx));
    unsigned short ly = f32_to_bf16_rn(v.y - bf16_to_f32(hy));
    size_t off0 = (size_t)k * D + lane * 2;
    u16x2 hv; hv[0] = hx; hv[1] = hy;
    u16x2 lv; lv[0] = lx; lv[1] = ly;
    *reinterpret_cast<u16x2*>(Cp + off0) = hv;
    *reinterpret_cast<u16x2*>(Cp + 131072 + off0) = lv;
}

// ---------------------------------------------------------------------------
// Fused argmin + epilogue. 512 blocks x 512 thr (8 waves).
// Wave (rg = w&3, ch = w>>2): rows rg*32..+32, column half ch (32 of 64 cw).
__global__ __launch_bounds__(512, 2) void vq_argmin_fused(
    const float* __restrict__ x,
    const unsigned short* __restrict__ Cp,
    const float* __restrict__ cnorm,
    const float* __restrict__ cw,
    float* __restrict__ out_idx_f,
    float* __restrict__ qout,
    float* __restrict__ rowloss,
    float* __restrict__ xnorm,
    int* __restrict__ rcnt,
    int* __restrict__ rrows,
    double* __restrict__ acc) {
    __shared__ unsigned char Bs[2][2][16384];  // [buf][plane][64cw * 256B swz]
    __shared__ float mv[2][128], mv2[2][128];
    __shared__ int mi[2][128];
    __shared__ int idx_s[128];
    __shared__ float xs_n[128];
    __shared__ double wsum[8];

    const int tid = threadIdx.x;
    const int wave = tid >> 6;
    const int lane = tid & 63;
    const int l15 = lane & 15;
    const int lg = lane >> 4;
    const int rg = wave & 3;   // row group
    const int ch = wave >> 2;  // column half
    const int base = blockIdx.x * 128;
    const int wrow = base + rg * 32;

    // Stage chunk c (64 cw x 2 planes = 32KB): 32 loads, 4 per wave.
    const char* Cpb = reinterpret_cast<const char*>(Cp);
    auto stageB = [&](int c, int b) {
#pragma unroll
        for (int u = 0; u < 4; ++u) {
            int t = wave * 4 + u;
            int pl = t >> 4;
            int cwl = (t & 15) * 4 + lg;
            int q = l15 * 16;
            const char* src = Cpb + pl * 262144 + ((size_t)(c * 64 + cwl)) * 256
                              + (q ^ ((cwl & 7) << 4));
            void* dst = (void*)&Bs[b][pl][(t & 15) * 1024];
            gload_lds16(src, dst);
        }
    };
    stageB(0, 0);

    // A fragments: f32 x -> bf16 hi/lo in regs; row sumsq alongside.
    // (Both column-half waves load the same A rows; only ch==0 writes norms.)
    bf16x8 A[2][4][2];
    float xn[2] = {0.f, 0.f};
#pragma unroll
    for (int r2 = 0; r2 < 2; ++r2) {
        const float* xr0 = x + (size_t)(wrow + r2 * 16 + l15) * D;
#pragma unroll
        for (int s = 0; s < 4; ++s) {
            const float4* xf = reinterpret_cast<const float4*>(xr0 + s * 32 + lg * 8);
            float4 f0 = xf[0];
            float4 f1 = xf[1];
            float in[8] = {f0.x, f0.y, f0.z, f0.w, f1.x, f1.y, f1.z, f1.w};
            u16x8 hv, lv;
#pragma unroll
            for (int e = 0; e < 8; ++e) {
                xn[r2] += in[e] * in[e];
                unsigned short h = f32_to_bf16_rn(in[e]);
                hv[e] = h;
                lv[e] = f32_to_bf16_rn(in[e] - bf16_to_f32(h));
            }
            A[r2][s][0] = *reinterpret_cast<bf16x8*>(&hv);
            A[r2][s][1] = *reinterpret_cast<bf16x8*>(&lv);
        }
    }
#pragma unroll
    for (int r2 = 0; r2 < 2; ++r2) {
        xn[r2] += __shfl_xor(xn[r2], 16, 64);
        xn[r2] += __shfl_xor(xn[r2], 32, 64);
        if (ch == 0 && lg == 0) {
            xs_n[rg * 32 + r2 * 16 + l15] = xn[r2];
            xnorm[wrow + r2 * 16 + l15] = xn[r2];
        }
    }

    float tv[2][4], tv2[2][4];
    int ti[2][4];
#pragma unroll
    for (int r2 = 0; r2 < 2; ++r2)
#pragma unroll
        for (int i = 0; i < 4; ++i) { tv[r2][i] = 3.4e38f; tv2[r2][i] = 3.4e38f; ti[r2][i] = 0; }

    const int cb = l15 * 256;
    const int swz = (l15 & 7) << 4;
    int kb[4];
#pragma unroll
    for (int s = 0; s < 4; ++s) kb[s] = (s * 64 + lg * 16) ^ swz;

    asm volatile("s_waitcnt vmcnt(0)" ::: "memory");
    __syncthreads();

    for (int c = 0; c < 16; ++c) {
        const int buf = c & 1;
        if (c < 15) stageB(c + 1, buf ^ 1);

        f32x4 accf[2][2];
#pragma unroll
        for (int r2 = 0; r2 < 2; ++r2)
#pragma unroll
            for (int j = 0; j < 2; ++j) accf[r2][j] = (f32x4)(0.f);

#pragma unroll
        for (int s = 0; s < 4; ++s) {
            bf16x8 bh[2], bl[2];
#pragma unroll
            for (int j = 0; j < 2; ++j) {
                int ad = (ch * 2 + j) * 4096 + cb + kb[s];
                bh[j] = *reinterpret_cast<const bf16x8*>(&Bs[buf][0][ad]);
                bl[j] = *reinterpret_cast<const bf16x8*>(&Bs[buf][1][ad]);
            }
#pragma unroll
            for (int r2 = 0; r2 < 2; ++r2)
#pragma unroll
                for (int j = 0; j < 2; ++j) {
                    accf[r2][j] = __builtin_amdgcn_mfma_f32_16x16x32_bf16(
                        A[r2][s][0], bh[j], accf[r2][j], 0, 0, 0);
                    accf[r2][j] = __builtin_amdgcn_mfma_f32_16x16x32_bf16(
                        A[r2][s][0], bl[j], accf[r2][j], 0, 0, 0);
                    accf[r2][j] = __builtin_amdgcn_mfma_f32_16x16x32_bf16(
                        A[r2][s][1], bh[j], accf[r2][j], 0, 0, 0);
                }
        }

        // scores + running top-2 (cols ascend per lane -> first-min kept)
#pragma unroll
        for (int j = 0; j < 2; ++j) {
            int col = c * 64 + (ch * 2 + j) * 16 + l15;
            float cn = cnorm[col];
#pragma unroll
            for (int r2 = 0; r2 < 2; ++r2)
#pragma unroll
                for (int i = 0; i < 4; ++i) {
                    float sc = cn - 2.f * accf[r2][j][i];
                    if (sc < tv[r2][i]) {
                        tv2[r2][i] = tv[r2][i];
                        tv[r2][i] = sc;
                        ti[r2][i] = col;
                    } else if (sc < tv2[r2][i]) {
                        tv2[r2][i] = sc;
                    }
                }
        }
        asm volatile("s_waitcnt vmcnt(0)" ::: "memory");
        __syncthreads();
    }

    // Per-wave cross-lane top-2 merge over the 16 l15 lanes; stash per half.
#pragma unroll
    for (int r2 = 0; r2 < 2; ++r2)
#pragma unroll
        for (int i = 0; i < 4; ++i) {
            float v = tv[r2][i], v2 = tv2[r2][i];
            int ix = ti[r2][i];
#pragma unroll
            for (int off = 1; off < 16; off <<= 1) {
                float ov = __shfl_xor(v, off, 64);
                float ov2 = __shfl_xor(v2, off, 64);
                int oi = __shfl_xor(ix, off, 64);
                float nv2 = fminf(fminf(v2, ov2), fmaxf(v, ov));
                if (ov < v || (ov == v && oi < ix)) { v = ov; ix = oi; }
                v2 = nv2;
            }
            if (l15 == 0) {
                int rl = rg * 32 + r2 * 16 + lg * 4 + i;
                mv[ch][rl] = v;
                mv2[ch][rl] = v2;
                mi[ch][rl] = ix;
            }
        }
    __syncthreads();

    // Cross-half merge (threads 0..127, one row each) + bookkeeping.
    double lsum = 0.0;
    if (tid < 128) {
        int row = base + tid;
        float v0 = mv[0][tid], v0b = mv2[0][tid];
        int i0 = mi[0][tid];
        float v1 = mv[1][tid], v1b = mv2[1][tid];
        int i1 = mi[1][tid];
        bool take0 = (v0 < v1) || (v0 == v1 && i0 <= i1);
        float best = take0 ? v0 : v1;
        int bidx = take0 ? i0 : i1;
        float second = take0 ? fminf(v1, v0b) : fminf(v0, v1b);

        out_idx_f[row] = (float)bidx;
        idx_s[tid] = bidx;
        float rl = xs_n[tid] + best;
        rowloss[row] = rl;
        lsum = (double)rl;
        if (second - best < MARGIN) {
            int p = atomicAdd(rcnt, 1);
            rrows[p] = row;
        }
    }

    // Block loss partial -> one f64 atomic.
#pragma unroll
    for (int off = 32; off; off >>= 1) lsum += __shfl_down(lsum, off, 64);
    if (lane == 0) wsum[wave] = lsum;
    __syncthreads();
    if (tid == 0) {
        double b = 0.0;
#pragma unroll
        for (int q = 0; q < 8; ++q) b += wsum[q];
        atomicAdd(acc, b);
    }

    // qout gather-write: 128 rows x 512B, coalesced; codebook is L2-hot.
    const float4* cw4 = reinterpret_cast<const float4*>(cw);
    float4* q4 = reinterpret_cast<float4*>(qout);
#pragma unroll
    for (int it = 0; it < 8; ++it) {
        int i = it * 512 + tid;
        int r = i >> 5, d4 = i & 31;
        q4[(size_t)(base + r) * 32 + d4] = cw4[(size_t)idx_s[r] * 32 + d4];
    }
}

// ---------------------------------------------------------------------------
// Batched exact repair: 16 flagged rows share one codebook stream. Updates
// idx/qout/rowloss; accumulates (new-old) loss deltas, 1 atomic per block.
__global__ __launch_bounds__(256) void vq_repair(const float* __restrict__ x,
                                                 const float* __restrict__ cw,
                                                 const float* __restrict__ cnorm,
                                                 const float* __restrict__ xnorm,
                                                 const int* __restrict__ rcnt,
                                                 const int* __restrict__ rrows,
                                                 float* __restrict__ out_idx_f,
                                                 float* __restrict__ qout,
                                                 float* __restrict__ rowloss,
                                                 double* __restrict__ acc) {
    __shared__ float xs[16][132];
    __shared__ int rowids[16];
    __shared__ float sval[16][16];
    __shared__ int sidx[16][16];
    __shared__ int fidx[16];

    const int t = threadIdx.x;
    const int count = *rcnt;
    const float4* cw4 = reinterpret_cast<const float4*>(cw);
    double dsum = 0.0;

    for (int g = blockIdx.x; g * 16 < count; g += 512) {
        int nrows = min(16, count - g * 16);
        __syncthreads();
        if (t < 16) rowids[t] = rrows[g * 16 + (t < nrows ? t : 0)];
        __syncthreads();
        for (int i = t; i < 512; i += 256) {
            int r = i >> 5, d4 = i & 31;
            *reinterpret_cast<float4*>(&xs[r][d4 * 4]) =
                reinterpret_cast<const float4*>(x)[(size_t)rowids[r] * 32 + d4];
        }
        __syncthreads();

        const int r = t & 15;
        const int qq = t >> 4;
        float bv = 3.4e38f;
        int bi = 0;
#pragma unroll 2
        for (int kt = 0; kt < 8; ++kt) {
            float a[8] = {0.f, 0.f, 0.f, 0.f, 0.f, 0.f, 0.f, 0.f};
            int k0 = qq * 64 + kt * 8;
            for (int d4 = 0; d4 < 32; ++d4) {
                float4 xv = *reinterpret_cast<const float4*>(&xs[r][d4 * 4]);
#pragma unroll
                for (int kk = 0; kk < 8; ++kk) {
                    float4 cv = cw4[(size_t)(k0 + kk) * 32 + d4];
                    a[kk] += xv.x * cv.x + xv.y * cv.y + xv.z * cv.z + xv.w * cv.w;
                }
            }
#pragma unroll
            for (int kk = 0; kk < 8; ++kk) {
                int k = k0 + kk;
                float sc = cnorm[k] - 2.f * a[kk];
                if (sc < bv) { bv = sc; bi = k; }
            }
        }
        sval[r][qq] = bv;
        sidx[r][qq] = bi;
        __syncthreads();
        if (t < 16) {
            float fv = sval[t][0];
            int fi = sidx[t][0];
#pragma unroll
            for (int q2 = 1; q2 < 16; ++q2) {
                float v = sval[t][q2];
                int ii = sidx[t][q2];
                if (v < fv || (v == fv && ii < fi)) { fv = v; fi = ii; }
            }
            fidx[t] = fi;
            if (t < nrows) {
                int row = rowids[t];
                out_idx_f[row] = (float)fi;
                float nrl = xnorm[row] + fv;
                float orl = rowloss[row];
                rowloss[row] = nrl;
                dsum += (double)nrl - (double)orl;
            }
        }
        __syncthreads();
        for (int i = t; i < 512; i += 256) {
            int rr = i >> 5, d4 = i & 31;
            float4 q4 = cw4[(size_t)fidx[rr] * 32 + d4];
            reinterpret_cast<float4*>(qout)[(size_t)rowids[rr] * 32 + d4] = q4;
        }
    }
#pragma unroll
    for (int off = 32; off; off >>= 1) dsum += __shfl_down(dsum, off, 64);
    __shared__ double wsum[4];
    if ((t & 63) == 0) wsum[t >> 6] = dsum;
    __syncthreads();
    if (t == 0) {
        double b = wsum[0] + wsum[1] + wsum[2] + wsum[3];
        if (b != 0.0) atomicAdd(acc, b);
    }
}

// ---------------------------------------------------------------------------
__global__ void vq_loss_final(const double* __restrict__ acc,
                              float* __restrict__ out_loss) {
    *out_loss = (float)(*acc * (1.25 / (double)((size_t)N_ROWS * D)));
}

// ---------------------------------------------------------------------------
extern "C" void kernel_launch(void* const* d_in, const int* in_sizes, int n_in,
                              void* d_out, int out_size, void* d_ws, size_t ws_size,
                              hipStream_t stream) {
    const float* x = (const float*)d_in[0];
    const float* cw = (const float*)d_in[1];

    float* qout = (float*)d_out;                                    // 8388608 f32
    float* out_idx_f = qout + (size_t)N_ROWS * D;                   // 65536 f32
    float* out_loss = out_idx_f + N_ROWS;                           // 1 f32

    char* w = (char*)d_ws;
    unsigned short* Cp = (unsigned short*)w;          w += 524288;
    float* cnorm = (float*)w;                         w += 4096;
    int* rcnt = (int*)w;                              w += 16;
    double* acc = (double*)w;                         w += 240;
    int* rrows = (int*)w;                             w += 262144;
    float* xnorm = (float*)w;                         w += 262144;
    float* rowloss = (float*)w;                       w += 262144;

    vq_prep_cw<<<K_CODES, 64, 0, stream>>>(cw, Cp, cnorm, rcnt, acc);
    vq_argmin_fused<<<N_ROWS / 128, 512, 0, stream>>>(
        x, Cp, cnorm, cw, out_idx_f, qout, rowloss, xnorm, rcnt, rrows, acc);
    vq_repair<<<512, 256, 0, stream>>>(
        x, cw, cnorm, xnorm, rcnt, rrows, out_idx_f, qout, rowloss, acc);
    vq_loss_final<<<1, 1, 0, stream>>>(acc, out_loss);
}